// Round 4
// baseline (72.054 us; speedup 1.0000x reference)
//
#include <hip/hip_runtime.h>
#include <math.h>

#define NN 256
#define DD 256
#define KK 16
#define M_MARGIN 0.6f
#define T_THRESH 0.0025f
#define EPS 1e-12f

// Kernel 1 (prep): one wave per row r. Coalesced float4 loads of yi[r] and
// yit[r]; shuffle-reduce ||y_r||^2, ||yt_r||^2, y_r.yt_r. Emits
//   invn[r]  = 1/sqrt(||y_r||^2 + EPS)
//   invnt[r] = 1/sqrt(||yt_r||^2 + EPS)
//   diit[r]  = 0.5*sqrt(max(2 - 2*c, 0) + EPS), c = cross*invn*invnt
// Block 0 also zeroes out[0] (replaces the memset node; stream-ordered
// before the main kernel's atomics).
__global__ void __launch_bounds__(256) prep_kernel(
    const float* __restrict__ yi, const float* __restrict__ yit,
    float* __restrict__ invn, float* __restrict__ invnt,
    float* __restrict__ diit, float* __restrict__ out)
{
    const int t    = threadIdx.x;
    const int lane = t & 63;
    const int row  = blockIdx.x * 4 + (t >> 6);

    const float4 a = ((const float4*)(yi  + row * DD))[lane];
    const float4 b = ((const float4*)(yit + row * DD))[lane];
    float r0 = (a.x * a.x + a.y * a.y) + (a.z * a.z + a.w * a.w);
    float r1 = (b.x * b.x + b.y * b.y) + (b.z * b.z + b.w * b.w);
    float r2 = (a.x * b.x + a.y * b.y) + (a.z * b.z + a.w * b.w);
    #pragma unroll
    for (int off = 32; off > 0; off >>= 1) {
        r0 += __shfl_down(r0, off, 64);
        r1 += __shfl_down(r1, off, 64);
        r2 += __shfl_down(r2, off, 64);
    }
    if (lane == 0) {
        const float iny  = 1.0f / sqrtf(r0 + EPS);
        const float inyt = 1.0f / sqrtf(r1 + EPS);
        invn [row] = iny;
        invnt[row] = inyt;
        const float c = r2 * iny * inyt;
        diit [row] = 0.5f * sqrtf(fmaxf(2.0f - 2.0f * c, 0.0f) + EPS);
    }
    if (blockIdx.x == 0 && t == 0) out[0] = 0.0f;
}

// Kernel 2 (main): block i handles row i. 512 threads: lane-pair (t, t^1)
// shares candidate j = t>>1, splitting the D-loop (interleaved float4 halves)
// and the rank scan. Gram identity + precomputed inverse norms: inner loop is
// just the two cross dots (8 FMA / float4).
__global__ void __launch_bounds__(512) blcd_main_kernel(
    const float* __restrict__ yi, const float* __restrict__ yit,
    const float* __restrict__ invn, const float* __restrict__ invnt,
    const float* __restrict__ diit, float* __restrict__ out)
{
    __shared__ float s_yi[DD];    // raw row i
    __shared__ float s_yit[DD];   // raw row i (tilde)
    __shared__ float sdis[NN];    // dis_yii[i][:]
    __shared__ float red[8];      // per-wave loss partials

    const int i = blockIdx.x;
    const int t = threadIdx.x;    // 0..511
    const int j = t >> 1;         // candidate row
    const int h = t & 1;          // which half of the D-range

    if (t < DD) {
        s_yi [t] = yi [i * DD + t];
        s_yit[t] = yit[i * DD + t];
    }
    const float inv_ni  = invn [i];   // uniform, L1 broadcast
    const float inv_nit = invnt[i];
    const float inv_nj  = invn [j];   // per-pair scalar
    __syncthreads();

    // Half D-loop: float4 index d4 = 2k + h  (lane-pairs read contiguous 32B).
    const float4* __restrict__ rj  = (const float4*)(yi + j * DD);
    const float4* __restrict__ si  = (const float4*)s_yi;
    const float4* __restrict__ sit = (const float4*)s_yit;
    float4 q4  = make_float4(0.f, 0.f, 0.f, 0.f);
    float4 qt4 = make_float4(0.f, 0.f, 0.f, 0.f);
    #pragma unroll 8
    for (int k = 0; k < DD / 8; ++k) {
        const int d4 = 2 * k + h;
        float4 y = rj[d4];
        float4 u = si[d4];
        float4 v = sit[d4];
        q4.x  += y.x * u.x; q4.y  += y.y * u.y; q4.z  += y.z * u.z; q4.w  += y.w * u.w;
        qt4.x += y.x * v.x; qt4.y += y.y * v.y; qt4.z += y.z * v.z; qt4.w += y.w * v.w;
    }
    float q  = (q4.x  + q4.y ) + (q4.z  + q4.w );
    float qt = (qt4.x + qt4.y) + (qt4.z + qt4.w);
    q  += __shfl_xor(q,  1, 64);   // combine the two halves (partner = t^1)
    qt += __shfl_xor(qt, 1, 64);

    const float c    = q  * inv_nj * inv_ni;
    const float ct   = qt * inv_nj * inv_nit;
    const float myv  = 0.5f * sqrtf(fmaxf(2.0f - 2.0f * c , 0.0f) + EPS);
    const float myvt = 0.5f * sqrtf(fmaxf(2.0f - 2.0f * ct, 0.0f) + EPS);
    if (h == 0) sdis[j] = myv;
    __syncthreads();

    // Stable rank == top_k position (ties -> lower index first), split per pair.
    int rank = 0;
    const float4* sd4 = (const float4*)sdis;
    #pragma unroll 8
    for (int k = h * (NN / 8); k < (h + 1) * (NN / 8); ++k) {
        float4 v = sd4[k];
        const int jj = k * 4;
        rank += (v.x < myv || (v.x == myv && (jj + 0) < j)) ? 1 : 0;
        rank += (v.y < myv || (v.y == myv && (jj + 1) < j)) ? 1 : 0;
        rank += (v.z < myv || (v.z == myv && (jj + 2) < j)) ? 1 : 0;
        rank += (v.w < myv || (v.w == myv && (jj + 3) < j)) ? 1 : 0;
    }
    rank += __shfl_xor(rank, 1, 64);

    float contrib = 0.0f;
    if (h == 0) {
        if (rank >= 1 && rank <= KK) {      // e1 term: j is one of the 16 nbrs
            const float dd = myv - myvt;
            contrib = dd * dd - T_THRESH;
        }
        if (rank == 1) {                    // e2 hinge: j is the 2nd-NN
            contrib += fmaxf(diit[i] + M_MARGIN - myv, 0.0f);
        }
    }

    // Block reduce (8 waves) + one atomic per block.
    #pragma unroll
    for (int off = 32; off > 0; off >>= 1) contrib += __shfl_down(contrib, off, 64);
    if ((t & 63) == 0) red[t >> 6] = contrib;
    __syncthreads();
    if (t == 0)
        atomicAdd(out, ((red[0] + red[1]) + (red[2] + red[3]))
                     + ((red[4] + red[5]) + (red[6] + red[7])));
}

extern "C" void kernel_launch(void* const* d_in, const int* in_sizes, int n_in,
                              void* d_out, int out_size, void* d_ws, size_t ws_size,
                              hipStream_t stream) {
    (void)in_sizes; (void)n_in; (void)out_size; (void)ws_size;

    const float* yi  = (const float*)d_in[0];
    const float* yit = (const float*)d_in[1];
    float* out = (float*)d_out;

    float* invn  = (float*)d_ws;          // 256 floats
    float* invnt = invn  + NN;            // 256 floats
    float* diit  = invnt + NN;            // 256 floats

    prep_kernel<<<NN / 4, 256, 0, stream>>>(yi, yit, invn, invnt, diit, out);
    blcd_main_kernel<<<NN, 512, 0, stream>>>(yi, yit, invn, invnt, diit, out);
}